// Round 6
// baseline (117.699 us; speedup 1.0000x reference)
//
#include <hip/hip_runtime.h>
#include <hip/hip_bf16.h>

// Problem constants
#define B_   4
#define N_   160
#define D_   64
#define ZI_  64
#define H1_  128
#define H2_  64
#define L_   4
#define LE_  8

typedef __bf16 bf16x8 __attribute__((ext_vector_type(8)));
typedef float  f32x4  __attribute__((ext_vector_type(4)));

// ---------------------------------------------------------------------------
// Stage A: per-(b,i) precompute (scalar; measured ~3 µs).
//   ui[b,i,h]   = ne[b,i]@Wi1[:64] + z_intra[b]@Wi1[128:192] + bi1      (fp32)
//   uq[b,l,i,h] = ne[b,i]@Wl1[:64] + z_inter[b]@Wl1[128:192] + lag[l]@Wl1_l + bl1
//   vpi[b,j,h]  = bf16( ne[b,j]@Wi1[64:128] )
//   vpl[b,j,h]  = bf16( ne[b,j]@Wl1[64:128] )
// Blocks 0/1 also emit Wi2/Wl2 as bf16 MFMA-B-fragment-ordered arrays.
// ---------------------------------------------------------------------------
__global__ __launch_bounds__(128) void stage_a(
    const float* __restrict__ ne,
    const float* __restrict__ zi,
    const float* __restrict__ ze,
    const float* __restrict__ lag,
    const float* __restrict__ Wi1,
    const float* __restrict__ bi1,
    const float* __restrict__ Wl1,
    const float* __restrict__ bl1,
    const float* __restrict__ Wi2,
    const float* __restrict__ Wl2,
    float* __restrict__ ui, float* __restrict__ uq,
    __bf16* __restrict__ vpi, __bf16* __restrict__ vpl,
    __bf16* __restrict__ W2fi, __bf16* __restrict__ W2fl)
{
    const int bi = blockIdx.x;       // b*N + i
    const int b  = bi / N_;
    const int h  = threadIdx.x;      // 0..127

    const float* nerow = ne + bi * D_;

    float pi_ = 0.f, pj_ = 0.f, qi_ = 0.f, qj_ = 0.f;
#pragma unroll 16
    for (int d = 0; d < D_; ++d) {
        const float a = nerow[d];
        pi_ += a * Wi1[d * H1_ + h];
        pj_ += a * Wi1[(D_ + d) * H1_ + h];
        qi_ += a * Wl1[d * H1_ + h];
        qj_ += a * Wl1[(D_ + d) * H1_ + h];
    }
    float pz = 0.f, qz = 0.f;
#pragma unroll 16
    for (int z = 0; z < ZI_; ++z) {
        pz += zi[b * ZI_ + z] * Wi1[(2 * D_ + z) * H1_ + h];
        qz += ze[b * ZI_ + z] * Wl1[(2 * D_ + z) * H1_ + h];
    }

    ui[bi * H1_ + h]  = pi_ + pz + bi1[h];
    vpi[bi * H1_ + h] = (__bf16)pj_;
    vpl[bi * H1_ + h] = (__bf16)qj_;

    const float qbase = qi_ + qz + bl1[h];
#pragma unroll
    for (int l = 0; l < L_; ++l) {
        float ql = 0.f;
#pragma unroll
        for (int e = 0; e < LE_; ++e)
            ql += lag[l * LE_ + e] * Wl1[(2 * D_ + ZI_ + e) * H1_ + h];
        uq[((b * L_ + l) * N_ + (bi % N_)) * H1_ + h] = qbase + ql;
    }

    // W2 -> bf16 fragment layout: chunk fc = (kt*4+ct)*64 + lane holds the 8
    // values lane needs for fragment (kt,ct).
    if (bi < 2) {
        const float* Wsrc = (bi == 0) ? Wi2 : Wl2;
        __bf16* Wdst = (bi == 0) ? W2fi : W2fl;
#pragma unroll
        for (int r = 0; r < 8; ++r) {
            const int fc = h + 128 * r;
            const int kt = fc >> 8, ct = (fc >> 6) & 3;
            const int q = (fc >> 4) & 3, c = fc & 15;
            bf16x8 t;
#pragma unroll
            for (int j = 0; j < 8; ++j)
                t[j] = (__bf16)Wsrc[(32 * kt + 8 * q + j) * H2_ + 16 * ct + c];
            *(bf16x8*)(Wdst + fc * 8) = t;
        }
    }
}

// ---------------------------------------------------------------------------
// Stage B (R6): deferred epilogue + j-split.
// Grid 1600 blocks x 256 thr. rowgrp = blk>>1 (4 consecutive row-ids, same
// batch/branch), half = blk&1 selects j in [80*half, 80*half+80) = 5 tiles.
// Panel: 80x128 bf16 in LDS (20 KB), XOR swizzle g' = g ^ (row&7).
// jt loop body: ds_read + a-build + 16 MFMA + 16 FMA partial into plog —
// NO shuffles / exp / stores in-loop (they were a ~600cyc serial chain per
// jt in R3-R5; with only ~3 waves/SIMD it was unhidden latency). All 20
// reduction chains run pipelined in one final phase.
// MFMA 16x16x32 layouts (HW-verified):
//   A: lane holds A[m=lane&15][k=8*(lane>>4)+j]
//   B: lane holds B[k=8*(lane>>4)+j][n=lane&15]
//   C/D: lane holds D[row=4*(lane>>4)+reg][col=lane&15]
// ---------------------------------------------------------------------------
__global__ __launch_bounds__(256, 2) void stage_b(
    const float* __restrict__ ui, const float* __restrict__ uq,
    const __bf16* __restrict__ vpi, const __bf16* __restrict__ vpl,
    const __bf16* __restrict__ W2fi, const __bf16* __restrict__ W2fl,
    const float* __restrict__ bi2, const float* __restrict__ bi3,
    const float* __restrict__ bl2, const float* __restrict__ bl3,
    const float* __restrict__ Wi3, const float* __restrict__ Wl3,
    float* __restrict__ out)
{
    __shared__ __bf16 panel[80 * H1_];   // 20480 B, swizzled

    const int t    = threadIdx.x;
    const int wid  = t >> 6;
    const int lane = t & 63;
    const int q = lane >> 4;
    const int c = lane & 15;

    const int blk    = blockIdx.x;       // 0..1599
    const int rowgrp = blk >> 1;         // 0..799
    const int half   = blk & 1;          // j-half
    const int wave   = rowgrp * 4 + wid; // row id 0..3199

    // Block-uniform panel + W2-fragment source.
    const __bf16 *psrc, *Wf;
    if (rowgrp < 160) { psrc = vpi + (rowgrp / 40) * (N_ * H1_);           Wf = W2fi; }
    else              { psrc = vpl + ((rowgrp - 160) / 160) * (N_ * H1_);  Wf = W2fl; }
    psrc += 80 * half * H1_;

    // Wave-specific row params.
    const float* ubase;
    const float *b2, *w3;
    const float* b3p;
    long  obase;
    int   i;
    if (wave < B_ * N_) {                      // intra: W_t
        i = wave % N_;
        ubase = ui + wave * H1_;
        b2 = bi2; w3 = Wi3; b3p = bi3;
        obase = (long)wave * N_;
    } else {                                   // inter: A_lags_t
        const int w2i = wave - B_ * N_;
        i = w2i % N_;
        ubase = uq + w2i * H1_;
        b2 = bl2; w3 = Wl3; b3p = bl3;
        obase = (long)B_ * N_ * N_ + (long)w2i * N_;
    }
    const float b3f = b3p[0];

    // 1) Panel global loads first (coalesced 16B per thread x 5).
    bf16x8 stg[5];
#pragma unroll
    for (int it = 0; it < 5; ++it)
        stg[it] = *(const bf16x8*)(psrc + 2048 * it + 8 * t);

    // 2) W2 fragments: 16 coalesced 16B loads, register-resident.
    bf16x8 bfr[4][4];
#pragma unroll
    for (int kt = 0; kt < 4; ++kt)
#pragma unroll
        for (int ct = 0; ct < 4; ++ct)
            bfr[kt][ct] = *(const bf16x8*)(Wf + ((kt * 4 + ct) * 64 + lane) * 8);

    f32x4 u0[4], u1[4];
#pragma unroll
    for (int kt = 0; kt < 4; ++kt) {
        const float* up = ubase + 32 * kt + 8 * q;
        u0[kt] = *(const f32x4*)(up);
        u1[kt] = *(const f32x4*)(up + 4);
    }

    float b2c[4], w3c[4];
#pragma unroll
    for (int ct = 0; ct < 4; ++ct) {
        b2c[ct] = b2[16 * ct + c];
        w3c[ct] = w3[16 * ct + c];
    }

    // 3) Swizzled LDS write (local rows 0..79; row&7 == (t>>4)&7).
    {
        const int gsw = (t & 15) ^ ((t >> 4) & 7);
        const int rowbase = (t >> 4) * H1_ + gsw * 8;
#pragma unroll
        for (int it = 0; it < 5; ++it)
            *(bf16x8*)(panel + 16 * it * H1_ + rowbase) = stg[it];
    }
    __syncthreads();

    // 4) Tile loop: MFMA + partial-dot only; epilogue deferred.
    float plog[5][4];
#pragma unroll
    for (int jtl = 0; jtl < 5; ++jtl) {
        const __bf16* prow = panel + (16 * jtl + c) * H1_;
        f32x4 acc[4];
#pragma unroll
        for (int ct = 0; ct < 4; ++ct)
            acc[ct] = (f32x4){b2c[ct], b2c[ct], b2c[ct], b2c[ct]};

#pragma unroll
        for (int kt = 0; kt < 4; ++kt) {
            const bf16x8 vb = *(const bf16x8*)(prow + (((4 * kt + q) ^ (c & 7)) << 3));
            bf16x8 a;
#pragma unroll
            for (int j = 0; j < 4; ++j) {
                a[j]     = (__bf16)fmaxf(u0[kt][j] + (float)vb[j],     0.f);
                a[4 + j] = (__bf16)fmaxf(u1[kt][j] + (float)vb[4 + j], 0.f);
            }
#pragma unroll
            for (int ct = 0; ct < 4; ++ct)
                acc[ct] = __builtin_amdgcn_mfma_f32_16x16x32_bf16(
                    a, bfr[kt][ct], acc[ct], 0, 0, 0);
        }

        // Per-lane partial: sum over this lane's 4 columns.
#pragma unroll
        for (int r = 0; r < 4; ++r) {
            float p = 0.f;
#pragma unroll
            for (int ct = 0; ct < 4; ++ct)
                p += fmaxf(acc[ct][r], 0.f) * w3c[ct];
            plog[jtl][r] = p;
        }
    }

    // 5) Batched reductions: 20 independent 4-step chains, fully pipelined.
#pragma unroll
    for (int jtl = 0; jtl < 5; ++jtl)
#pragma unroll
        for (int r = 0; r < 4; ++r) {
            float p = plog[jtl][r];
            p += __shfl_xor(p, 1);
            p += __shfl_xor(p, 2);
            p += __shfl_xor(p, 4);
            p += __shfl_xor(p, 8);
            plog[jtl][r] = p;
        }

    // 6) Sigmoid + mask + store (lanes c<4; 16 lanes cover 16 consecutive j).
    if (c < 4) {
#pragma unroll
        for (int jtl = 0; jtl < 5; ++jtl) {
            float lg = plog[jtl][0];
            lg = (c == 1) ? plog[jtl][1] : lg;
            lg = (c == 2) ? plog[jtl][2] : lg;
            lg = (c == 3) ? plog[jtl][3] : lg;
            lg += b3f;
            const int j = 80 * half + 16 * jtl + 4 * q + c;
            const float s = (j == i) ? 0.f : 1.f / (1.f + __expf(-lg));
            out[obase + j] = s;
        }
    }
}

// ---------------------------------------------------------------------------
extern "C" void kernel_launch(void* const* d_in, const int* in_sizes, int n_in,
                              void* d_out, int out_size, void* d_ws, size_t ws_size,
                              hipStream_t stream) {
    const float* ne  = (const float*)d_in[0];
    const float* zi  = (const float*)d_in[1];
    const float* ze  = (const float*)d_in[2];
    const float* lag = (const float*)d_in[3];
    const float* Wi1 = (const float*)d_in[4];
    const float* bi1 = (const float*)d_in[5];
    const float* Wi2 = (const float*)d_in[6];
    const float* bi2 = (const float*)d_in[7];
    const float* Wi3 = (const float*)d_in[8];
    const float* bi3 = (const float*)d_in[9];
    const float* Wl1 = (const float*)d_in[10];
    const float* bl1 = (const float*)d_in[11];
    const float* Wl2 = (const float*)d_in[12];
    const float* bl2 = (const float*)d_in[13];
    const float* Wl3 = (const float*)d_in[14];
    const float* bl3 = (const float*)d_in[15];

    float*  ws   = (float*)d_ws;
    float*  ui   = ws;                         // 640*128 fp32
    float*  uqw  = ws + 81920;                 // 2560*128 fp32
    __bf16* vpi  = (__bf16*)(ws + 409600);     // 640*128 bf16
    __bf16* vpl  = vpi + 81920;                // 640*128 bf16
    __bf16* W2fi = (__bf16*)(ws + 491520);     // 8192 bf16 (fragment order)
    __bf16* W2fl = W2fi + 8192;                // 8192 bf16

    stage_a<<<B_ * N_, 128, 0, stream>>>(ne, zi, ze, lag, Wi1, bi1, Wl1, bl1,
                                         Wi2, Wl2, ui, uqw, vpi, vpl, W2fi, W2fl);

    stage_b<<<2 * (B_ * N_ + B_ * L_ * N_) / 4, 256, 0, stream>>>(
        ui, uqw, vpi, vpl, W2fi, W2fl,
        bi2, bi3, bl2, bl3, Wi3, Wl3,
        (float*)d_out);
}